// Round 15
// baseline (136.241 us; speedup 1.0000x reference)
//
#include <hip/hip_runtime.h>

#define DEV __device__ __forceinline__

typedef __attribute__((ext_vector_type(4))) float  f32x4;
typedef __attribute__((ext_vector_type(8))) short  short8v;
typedef __attribute__((ext_vector_type(4))) short  short4v;

// Problem sizes (fixed by the reference)
static constexpr int Bq = 2, Lq = 512, Dq = 512, Pq = 64, Hq = 2048;
static constexpr int BLq = Bq * Lq;  // 1024
static constexpr float INV2PI = 0.15915494309189535f;

DEV short f2bf(float f) {
  unsigned u = __float_as_uint(f);
  u += 0x7fffu + ((u >> 16) & 1u);
  return (short)(u >> 16);
}
DEV float bf2f(short s) {
  return __uint_as_float(((unsigned)(unsigned short)s) << 16);
}

// cos of t given in REVOLUTIONS (arg pre-scaled by 1/2pi)
DEV float cos_rev(float t) {
#if __has_builtin(__builtin_amdgcn_fractf) && __has_builtin(__builtin_amdgcn_cosf)
  return __builtin_amdgcn_cosf(__builtin_amdgcn_fractf(t));
#else
  return __cosf((t - floorf(t)) * 6.283185307179586f);
#endif
}

// async global->LDS, 16B/lane; LDS dest linear in lane (wave base + lane*16)
DEV void gload_lds16(const void* g, void* l) {
  __builtin_amdgcn_global_load_lds(
      (const __attribute__((address_space(1))) void*)g,
      (__attribute__((address_space(3))) void*)l, 16, 0, 0);
}

// ---------------------------------------------------------------------------
// Kernel A: fused prologue. Role-split by blockIdx.x. Gate first:
//   [0,1024)    gate: 8 bl-rows x 256 h per block; w/b prefetched across p
//   [1024,2048) transpose W_up  f32[512][2048]  -> wupT bf16[2048][512]
//   [2048,3072) transpose Wdr   f32[2048][512]  -> wdrT bf16[512][2048]
//   [3072,3200) transpose Wdi   f32[2048][64]   -> wdiT bf16[64][2048]
//   [3200,3712) cvt x_real -> xrbf bf16
__global__ __launch_bounds__(256) void fused_prologue(
    const float* __restrict__ x_real, const float* __restrict__ x_imag,
    const float* __restrict__ pos_freq,
    const float* __restrict__ W_up, const float* __restrict__ wq,
    const float* __restrict__ bq, const float* __restrict__ Wdr,
    const float* __restrict__ Wdi,
    short* __restrict__ wupT, short* __restrict__ wdrT,
    short* __restrict__ wdiT, short* __restrict__ xrbf,
    short* __restrict__ gate) {
  __shared__ __align__(16) float smem[32 * 33];
  const int b = blockIdx.x, tid = threadIdx.x;

  if (b < 1024) {  // --- gate ---
    constexpr int BLT = 8;
    float (*tc)[64] = (float(*)[64])smem;
    const int bl0 = (b & 127) * BLT;
    const int h = (b >> 7) * 256 + tid;

#pragma unroll
    for (int e = 0; e < BLT * 64 / 256; ++e) {  // 2 elems/thread
      int f = tid + 256 * e;
      int r = f >> 6, p = f & 63;
      int bl = bl0 + r;
      int l = bl & (Lq - 1);  // bl = bq*L + l
      tc[r][p] = x_imag[bl * Pq + p] * pos_freq[l * Pq + p];
    }
    __syncthreads();

    const float* wp = wq + h;
    const float* bp = bq + h;
    float acc[BLT] = {};
    // current-step coefficients (pre-scaled by 1/2pi)
    float cw0 = wp[0 * Hq] * INV2PI, cw1 = wp[1 * Hq] * INV2PI;
    float cw2 = wp[2 * Hq] * INV2PI, cw3 = wp[3 * Hq] * INV2PI;
    float cb0 = bp[0 * Hq] * INV2PI, cb1 = bp[1 * Hq] * INV2PI;
    float cb2 = bp[2 * Hq] * INV2PI, cb3 = bp[3 * Hq] * INV2PI;
#pragma unroll 1
    for (int p = 0; p < Pq; p += 4) {
      // prefetch next step's 8 coefficients while computing this step
      float nw0, nw1, nw2, nw3, nb0, nb1, nb2, nb3;
      if (p + 4 < Pq) {
        nw0 = wp[(p + 4) * Hq]; nw1 = wp[(p + 5) * Hq];
        nw2 = wp[(p + 6) * Hq]; nw3 = wp[(p + 7) * Hq];
        nb0 = bp[(p + 4) * Hq]; nb1 = bp[(p + 5) * Hq];
        nb2 = bp[(p + 6) * Hq]; nb3 = bp[(p + 7) * Hq];
      } else {
        nw0 = nw1 = nw2 = nw3 = nb0 = nb1 = nb2 = nb3 = 0.f;
      }
#pragma unroll
      for (int r = 0; r < BLT; ++r) {
        f32x4 t = *(const f32x4*)&tc[r][p];
        acc[r] += cos_rev(t.x * cw0 + cb0);
        acc[r] += cos_rev(t.y * cw1 + cb1);
        acc[r] += cos_rev(t.z * cw2 + cb2);
        acc[r] += cos_rev(t.w * cw3 + cb3);
      }
      cw0 = nw0 * INV2PI; cw1 = nw1 * INV2PI;
      cw2 = nw2 * INV2PI; cw3 = nw3 * INV2PI;
      cb0 = nb0 * INV2PI; cb1 = nb1 * INV2PI;
      cb2 = nb2 * INV2PI; cb3 = nb3 * INV2PI;
    }
#pragma unroll
    for (int r = 0; r < BLT; ++r)
      gate[(bl0 + r) * Hq + h] = f2bf(acc[r] * 0.125f);

  } else if (b < 3200) {  // --- transpose roles ---
    const int bb = b - 1024;
    const float* in; short* out; int R, C, c0, r0;
    if (bb < 1024)      { in = W_up; out = wupT; R = 512;  C = 2048; c0 = (bb & 63) * 32; r0 = (bb >> 6) * 32; }
    else if (bb < 2048) { int t2 = bb - 1024; in = Wdr; out = wdrT; R = 2048; C = 512; c0 = (t2 & 15) * 32; r0 = (t2 >> 4) * 32; }
    else                { int t2 = bb - 2048; in = Wdi; out = wdiT; R = 2048; C = 64;  c0 = (t2 & 1) * 32;  r0 = (t2 >> 1) * 32; }
    float (*tile)[33] = (float(*)[33])smem;
    const int tx = tid & 31, ty = tid >> 5;  // 32 x 8
#pragma unroll
    for (int i = 0; i < 4; ++i)
      tile[ty + 8 * i][tx] = in[(r0 + ty + 8 * i) * C + c0 + tx];
    __syncthreads();
#pragma unroll
    for (int i = 0; i < 4; ++i)
      out[(c0 + ty + 8 * i) * R + r0 + tx] = f2bf(tile[tx][ty + 8 * i]);

  } else {  // --- cvt x_real ---
    const int i = ((b - 3200) * 256 + tid) * 4;
    f32x4 v = *(const f32x4*)&x_real[i];
    short4v s;
    s.x = f2bf(v.x); s.y = f2bf(v.y); s.z = f2bf(v.z); s.w = f2bf(v.w);
    *(short4v*)&xrbf[i] = s;
  }
}

// ---------------------------------------------------------------------------
// SINGLE-buffered MFMA tile core (m97-pattern: stage -> sync -> compute ->
// sync). The R6 double-buffered variant raced intermittently (R13 post-timing
// divergence); this 2-barrier structure is the validated pattern (learn_hip
// m97 refcheck + this session's R5-source full-harness pass). BM=32 x BN=64,
// K-steps of 32; 4 waves (wr: 16-row half, wc: 32-col half).
template <int NSTEPS>
DEV void mfma_core(const short* __restrict__ Arow, int lda,
                   const short* __restrict__ Brow, int ldb,
                   short* As, short* Bs, int tid, f32x4* acc) {
  const int lane = tid & 63;
  const int wv = tid >> 6, wr = wv >> 1, wc = wv & 1;
  const int lrow = lane & 15, lk = (lane >> 4) * 8;
  const int srow = tid >> 2, sseg = (tid & 3) * 8;

#pragma unroll 1
  for (int t = 0; t < NSTEPS; ++t) {
    const int k0 = t * 32;
    if (tid < 128)  // A-tile: 32 rows x 32 k = 128 lanes x 16B
      gload_lds16(&Arow[srow * lda + k0 + sseg], &As[tid * 8]);
    gload_lds16(&Brow[srow * ldb + k0 + sseg], &Bs[tid * 8]);
    __syncthreads();  // drains vmcnt: staged data visible

    short8v a  = *(const short8v*)&As[(wr * 16 + lrow) * 32 + lk];
    short8v b0 = *(const short8v*)&Bs[(wc * 32 + lrow) * 32 + lk];
    short8v b1 = *(const short8v*)&Bs[(wc * 32 + 16 + lrow) * 32 + lk];
    acc[0] = __builtin_amdgcn_mfma_f32_16x16x32_bf16(a, b0, acc[0], 0, 0, 0);
    acc[1] = __builtin_amdgcn_mfma_f32_16x16x32_bf16(a, b1, acc[1], 0, 0, 0);
    __syncthreads();  // all ds_reads done before next overwrite
  }
}

// Kernel B: out(bf16) = (x_real @ W_up) * gate.  grid 32m x 32n = 1024.
__global__ __launch_bounds__(256) void fused_up(
    const short* __restrict__ xrbf, const short* __restrict__ wupT,
    const short* __restrict__ gate, short* __restrict__ outbf) {
  __shared__ __align__(16) short As[32 * 32];
  __shared__ __align__(16) short Bs[64 * 32];
  const int tid = threadIdx.x;
  const int m0 = (blockIdx.x >> 5) * 32, n0 = (blockIdx.x & 31) * 64;
  const int lane = tid & 63, wv = tid >> 6, wr = wv >> 1, wc = wv & 1;
  const int lrow = lane & 15;

  f32x4 acc[2] = {};
  mfma_core<16>(&xrbf[m0 * Dq], Dq, &wupT[n0 * Dq], Dq, As, Bs, tid, acc);

#pragma unroll
  for (int j = 0; j < 2; ++j)
#pragma unroll
    for (int r = 0; r < 4; ++r) {
      int row = m0 + wr * 16 + (lane >> 4) * 4 + r;
      int col = n0 + wc * 32 + j * 16 + lrow;
      outbf[row * Hq + col] = f2bf(acc[j][r] * bf2f(gate[row * Hq + col]));
    }
}

// Kernel C: role-split.
//   [0,256):   out_real = x_real + out @ W_down_real   (32m x 8n tiles)
//   [256,288): out_imag = x_imag + gate @ W_down_imag  (32m tiles, N=64)
__global__ __launch_bounds__(256) void fused_down(
    const short* __restrict__ outbf, const short* __restrict__ wdrT,
    const short* __restrict__ gate, const short* __restrict__ wdiT,
    const float* __restrict__ x_real, const float* __restrict__ x_imag,
    float* __restrict__ out_real, float* __restrict__ out_imag) {
  __shared__ __align__(16) short As[32 * 32];
  __shared__ __align__(16) short Bs[64 * 32];
  const int b = blockIdx.x, tid = threadIdx.x;
  const int lane = tid & 63, wv = tid >> 6, wr = wv >> 1, wc = wv & 1;
  const int lrow = lane & 15;
  f32x4 acc[2] = {};

  if (b < 256) {
    const int m0 = (b >> 3) * 32, n0 = (b & 7) * 64;
    mfma_core<64>(&outbf[m0 * Hq], Hq, &wdrT[n0 * Hq], Hq, As, Bs, tid, acc);
#pragma unroll
    for (int j = 0; j < 2; ++j)
#pragma unroll
      for (int r = 0; r < 4; ++r) {
        int row = m0 + wr * 16 + (lane >> 4) * 4 + r;
        int col = n0 + wc * 32 + j * 16 + lrow;
        out_real[row * Dq + col] = x_real[row * Dq + col] + acc[j][r];
      }
  } else {
    const int m0 = (b - 256) * 32;
    mfma_core<64>(&gate[m0 * Hq], Hq, wdiT, Hq, As, Bs, tid, acc);
#pragma unroll
    for (int j = 0; j < 2; ++j)
#pragma unroll
      for (int r = 0; r < 4; ++r) {
        int row = m0 + wr * 16 + (lane >> 4) * 4 + r;
        int col = wc * 32 + j * 16 + lrow;  // N = 64 = P
        out_imag[row * Pq + col] = x_imag[row * Pq + col] + acc[j][r];
      }
  }
}

// ---------------------------------------------------------------------------
extern "C" void kernel_launch(void* const* d_in, const int* in_sizes, int n_in,
                              void* d_out, int out_size, void* d_ws,
                              size_t ws_size, hipStream_t stream) {
  const float* x_real   = (const float*)d_in[0];  // (B,L,D)
  const float* x_imag   = (const float*)d_in[1];  // (B,L,P)
  const float* pos_freq = (const float*)d_in[2];  // (L,P)
  const float* W_up     = (const float*)d_in[3];  // (D,H)
  const float* wq       = (const float*)d_in[4];  // (P,H)
  const float* bq       = (const float*)d_in[5];  // (P,H)
  const float* Wdr      = (const float*)d_in[6];  // (H,D)
  const float* Wdi      = (const float*)d_in[7];  // (H,P)

  float* out_real = (float*)d_out;            // (B,L,D)
  float* out_imag = out_real + BLq * Dq;      // (B,L,P)

  char* ws = (char*)d_ws;
  short* gate_bf = (short*)ws;                      // 4 MB  [BL][H] bf16
  short* outbf   = (short*)(ws + (4u << 20));       // 4 MB  [BL][H] bf16
  short* wupT    = (short*)(ws + (8u << 20));       // 2 MB  [H][D]  bf16
  short* wdrT    = (short*)(ws + (10u << 20));      // 2 MB  [D][H]  bf16
  short* xrbf    = (short*)(ws + (12u << 20));      // 1 MB  [BL][D] bf16
  short* wdiT    = (short*)(ws + (13u << 20));      // 256KB [P][H]  bf16

  fused_prologue<<<3712, 256, 0, stream>>>(
      x_real, x_imag, pos_freq, W_up, wq, bq, Wdr, Wdi,
      wupT, wdrT, wdiT, xrbf, gate_bf);

  fused_up<<<1024, 256, 0, stream>>>(xrbf, wupT, gate_bf, outbf);

  fused_down<<<288, 256, 0, stream>>>(
      outbf, wdrT, gate_bf, wdiT, x_real, x_imag, out_real, out_imag);
}

// Round 16
// 125.287 us; speedup vs baseline: 1.0874x; 1.0874x over previous
//
#include <hip/hip_runtime.h>

#define DEV __device__ __forceinline__

typedef __attribute__((ext_vector_type(4))) float  f32x4;
typedef __attribute__((ext_vector_type(8))) short  short8v;
typedef __attribute__((ext_vector_type(4))) short  short4v;

// Problem sizes (fixed by the reference)
static constexpr int Bq = 2, Lq = 512, Dq = 512, Pq = 64, Hq = 2048;
static constexpr int BLq = Bq * Lq;  // 1024
static constexpr float INV2PI = 0.15915494309189535f;

DEV short f2bf(float f) {
  unsigned u = __float_as_uint(f);
  u += 0x7fffu + ((u >> 16) & 1u);
  return (short)(u >> 16);
}
DEV float bf2f(short s) {
  return __uint_as_float(((unsigned)(unsigned short)s) << 16);
}

// cos of t given in REVOLUTIONS (arg pre-scaled by 1/2pi)
DEV float cos_rev(float t) {
#if __has_builtin(__builtin_amdgcn_fractf) && __has_builtin(__builtin_amdgcn_cosf)
  return __builtin_amdgcn_cosf(__builtin_amdgcn_fractf(t));
#else
  return __cosf((t - floorf(t)) * 6.283185307179586f);
#endif
}

// async global->LDS, 16B/lane; LDS dest linear in lane (wave base + lane*16)
DEV void gload_lds16(const void* g, void* l) {
  __builtin_amdgcn_global_load_lds(
      (const __attribute__((address_space(1))) void*)g,
      (__attribute__((address_space(3))) void*)l, 16, 0, 0);
}

// ---------------------------------------------------------------------------
// Kernel A: fused prologue. Role-split by blockIdx.x. Gate first:
//   [0,1024)    gate: 8 bl-rows x 256 h per block; w/b prefetched across p
//   [1024,2048) transpose W_up  f32[512][2048]  -> wupT bf16[2048][512]
//   [2048,3072) transpose Wdr   f32[2048][512]  -> wdrT bf16[512][2048]
//   [3072,3200) transpose Wdi   f32[2048][64]   -> wdiT bf16[64][2048]
//   [3200,3712) cvt x_real -> xrbf bf16
__global__ __launch_bounds__(256) void fused_prologue(
    const float* __restrict__ x_real, const float* __restrict__ x_imag,
    const float* __restrict__ pos_freq,
    const float* __restrict__ W_up, const float* __restrict__ wq,
    const float* __restrict__ bq, const float* __restrict__ Wdr,
    const float* __restrict__ Wdi,
    short* __restrict__ wupT, short* __restrict__ wdrT,
    short* __restrict__ wdiT, short* __restrict__ xrbf,
    short* __restrict__ gate) {
  __shared__ __align__(16) float smem[32 * 33];
  const int b = blockIdx.x, tid = threadIdx.x;

  if (b < 1024) {  // --- gate ---
    constexpr int BLT = 8;
    float (*tc)[64] = (float(*)[64])smem;
    const int bl0 = (b & 127) * BLT;
    const int h = (b >> 7) * 256 + tid;

#pragma unroll
    for (int e = 0; e < BLT * 64 / 256; ++e) {  // 2 elems/thread
      int f = tid + 256 * e;
      int r = f >> 6, p = f & 63;
      int bl = bl0 + r;
      int l = bl & (Lq - 1);  // bl = bq*L + l
      tc[r][p] = x_imag[bl * Pq + p] * pos_freq[l * Pq + p];
    }
    __syncthreads();

    const float* wp = wq + h;
    const float* bp = bq + h;
    float acc[BLT] = {};
    // current-step coefficients (pre-scaled by 1/2pi)
    float cw0 = wp[0 * Hq] * INV2PI, cw1 = wp[1 * Hq] * INV2PI;
    float cw2 = wp[2 * Hq] * INV2PI, cw3 = wp[3 * Hq] * INV2PI;
    float cb0 = bp[0 * Hq] * INV2PI, cb1 = bp[1 * Hq] * INV2PI;
    float cb2 = bp[2 * Hq] * INV2PI, cb3 = bp[3 * Hq] * INV2PI;
#pragma unroll 1
    for (int p = 0; p < Pq; p += 4) {
      // prefetch next step's 8 coefficients while computing this step
      float nw0, nw1, nw2, nw3, nb0, nb1, nb2, nb3;
      if (p + 4 < Pq) {
        nw0 = wp[(p + 4) * Hq]; nw1 = wp[(p + 5) * Hq];
        nw2 = wp[(p + 6) * Hq]; nw3 = wp[(p + 7) * Hq];
        nb0 = bp[(p + 4) * Hq]; nb1 = bp[(p + 5) * Hq];
        nb2 = bp[(p + 6) * Hq]; nb3 = bp[(p + 7) * Hq];
      } else {
        nw0 = nw1 = nw2 = nw3 = nb0 = nb1 = nb2 = nb3 = 0.f;
      }
#pragma unroll
      for (int r = 0; r < BLT; ++r) {
        f32x4 t = *(const f32x4*)&tc[r][p];
        acc[r] += cos_rev(t.x * cw0 + cb0);
        acc[r] += cos_rev(t.y * cw1 + cb1);
        acc[r] += cos_rev(t.z * cw2 + cb2);
        acc[r] += cos_rev(t.w * cw3 + cb3);
      }
      cw0 = nw0 * INV2PI; cw1 = nw1 * INV2PI;
      cw2 = nw2 * INV2PI; cw3 = nw3 * INV2PI;
      cb0 = nb0 * INV2PI; cb1 = nb1 * INV2PI;
      cb2 = nb2 * INV2PI; cb3 = nb3 * INV2PI;
    }
#pragma unroll
    for (int r = 0; r < BLT; ++r)
      gate[(bl0 + r) * Hq + h] = f2bf(acc[r] * 0.125f);

  } else if (b < 3200) {  // --- transpose roles ---
    const int bb = b - 1024;
    const float* in; short* out; int R, C, c0, r0;
    if (bb < 1024)      { in = W_up; out = wupT; R = 512;  C = 2048; c0 = (bb & 63) * 32; r0 = (bb >> 6) * 32; }
    else if (bb < 2048) { int t2 = bb - 1024; in = Wdr; out = wdrT; R = 2048; C = 512; c0 = (t2 & 15) * 32; r0 = (t2 >> 4) * 32; }
    else                { int t2 = bb - 2048; in = Wdi; out = wdiT; R = 2048; C = 64;  c0 = (t2 & 1) * 32;  r0 = (t2 >> 1) * 32; }
    float (*tile)[33] = (float(*)[33])smem;
    const int tx = tid & 31, ty = tid >> 5;  // 32 x 8
#pragma unroll
    for (int i = 0; i < 4; ++i)
      tile[ty + 8 * i][tx] = in[(r0 + ty + 8 * i) * C + c0 + tx];
    __syncthreads();
#pragma unroll
    for (int i = 0; i < 4; ++i)
      out[(c0 + ty + 8 * i) * R + r0 + tx] = f2bf(tile[tx][ty + 8 * i]);

  } else {  // --- cvt x_real ---
    const int i = ((b - 3200) * 256 + tid) * 4;
    f32x4 v = *(const f32x4*)&x_real[i];
    short4v s;
    s.x = f2bf(v.x); s.y = f2bf(v.y); s.z = f2bf(v.z); s.w = f2bf(v.w);
    *(short4v*)&xrbf[i] = s;
  }
}

// ---------------------------------------------------------------------------
// SINGLE-buffered MFMA tile core, BK=64 (two 32-k panels per iteration).
// Sync pattern unchanged from the validated m97-style structure:
// stage -> sync -> compute -> sync. Halves the barrier/latency-exposed step
// count vs BK=32 (fused_down 64->32 steps, fused_up 16->8).
// LDS layout: A = [2 panels][32 rows][32 shorts] (4 KB),
//             B = [2 panels][64 rows][32 shorts] (8 KB).
// Staging dest stays EXACTLY linear in lane (tid*16 B); panel routing is done
// on the GLOBAL source address (m173 pattern: pre-swizzle source, linear LDS).
// Fragment reads keep the proven stride-32-short pattern (0 bank conflicts
// measured all session).
template <int NSTEPS>
DEV void mfma_core(const short* __restrict__ Arow, int lda,
                   const short* __restrict__ Brow, int ldb,
                   short* As, short* Bs, int tid, f32x4* acc) {
  const int lane = tid & 63;
  const int wv = tid >> 6, wr = wv >> 1, wc = wv & 1;
  const int lrow = lane & 15, lk = (lane >> 4) * 8;
  const int arow = (tid >> 2) & 31, apan = (tid >> 7) * 32, aseg = (tid & 3) * 8;
  const int brow = tid >> 2,        bseg = (tid & 3) * 8;

#pragma unroll 1
  for (int t = 0; t < NSTEPS; ++t) {
    const int k0 = t * 64;
    // A-tile: 32 rows x 64 k; thread tid -> panel (tid>>7), row, seg
    gload_lds16(&Arow[arow * lda + k0 + apan + aseg], &As[tid * 8]);
    // B-tile: 64 rows x 64 k; call i covers k-panel i for all 64 rows
    gload_lds16(&Brow[brow * ldb + k0 + bseg], &Bs[tid * 8]);
    gload_lds16(&Brow[brow * ldb + k0 + 32 + bseg], &Bs[2048 + tid * 8]);
    __syncthreads();  // drains vmcnt: staged data visible

#pragma unroll
    for (int kk = 0; kk < 2; ++kk) {
      short8v a  = *(const short8v*)&As[kk * 1024 + (wr * 16 + lrow) * 32 + lk];
      short8v b0 = *(const short8v*)&Bs[kk * 2048 + (wc * 32 + lrow) * 32 + lk];
      short8v b1 = *(const short8v*)&Bs[kk * 2048 + (wc * 32 + 16 + lrow) * 32 + lk];
      acc[0] = __builtin_amdgcn_mfma_f32_16x16x32_bf16(a, b0, acc[0], 0, 0, 0);
      acc[1] = __builtin_amdgcn_mfma_f32_16x16x32_bf16(a, b1, acc[1], 0, 0, 0);
    }
    __syncthreads();  // all ds_reads done before next overwrite
  }
}

// Kernel B: out(bf16) = (x_real @ W_up) * gate.  grid 32m x 32n = 1024.
__global__ __launch_bounds__(256) void fused_up(
    const short* __restrict__ xrbf, const short* __restrict__ wupT,
    const short* __restrict__ gate, short* __restrict__ outbf) {
  __shared__ __align__(16) short As[2 * 32 * 32];
  __shared__ __align__(16) short Bs[2 * 64 * 32];
  const int tid = threadIdx.x;
  const int m0 = (blockIdx.x >> 5) * 32, n0 = (blockIdx.x & 31) * 64;
  const int lane = tid & 63, wv = tid >> 6, wr = wv >> 1, wc = wv & 1;
  const int lrow = lane & 15;

  f32x4 acc[2] = {};
  mfma_core<8>(&xrbf[m0 * Dq], Dq, &wupT[n0 * Dq], Dq, As, Bs, tid, acc);

#pragma unroll
  for (int j = 0; j < 2; ++j)
#pragma unroll
    for (int r = 0; r < 4; ++r) {
      int row = m0 + wr * 16 + (lane >> 4) * 4 + r;
      int col = n0 + wc * 32 + j * 16 + lrow;
      outbf[row * Hq + col] = f2bf(acc[j][r] * bf2f(gate[row * Hq + col]));
    }
}

// Kernel C: role-split.
//   [0,256):   out_real = x_real + out @ W_down_real   (32m x 8n tiles)
//   [256,288): out_imag = x_imag + gate @ W_down_imag  (32m tiles, N=64)
__global__ __launch_bounds__(256) void fused_down(
    const short* __restrict__ outbf, const short* __restrict__ wdrT,
    const short* __restrict__ gate, const short* __restrict__ wdiT,
    const float* __restrict__ x_real, const float* __restrict__ x_imag,
    float* __restrict__ out_real, float* __restrict__ out_imag) {
  __shared__ __align__(16) short As[2 * 32 * 32];
  __shared__ __align__(16) short Bs[2 * 64 * 32];
  const int b = blockIdx.x, tid = threadIdx.x;
  const int lane = tid & 63, wv = tid >> 6, wr = wv >> 1, wc = wv & 1;
  const int lrow = lane & 15;
  f32x4 acc[2] = {};

  if (b < 256) {
    const int m0 = (b >> 3) * 32, n0 = (b & 7) * 64;
    mfma_core<32>(&outbf[m0 * Hq], Hq, &wdrT[n0 * Hq], Hq, As, Bs, tid, acc);
#pragma unroll
    for (int j = 0; j < 2; ++j)
#pragma unroll
      for (int r = 0; r < 4; ++r) {
        int row = m0 + wr * 16 + (lane >> 4) * 4 + r;
        int col = n0 + wc * 32 + j * 16 + lrow;
        out_real[row * Dq + col] = x_real[row * Dq + col] + acc[j][r];
      }
  } else {
    const int m0 = (b - 256) * 32;
    mfma_core<32>(&gate[m0 * Hq], Hq, wdiT, Hq, As, Bs, tid, acc);
#pragma unroll
    for (int j = 0; j < 2; ++j)
#pragma unroll
      for (int r = 0; r < 4; ++r) {
        int row = m0 + wr * 16 + (lane >> 4) * 4 + r;
        int col = wc * 32 + j * 16 + lrow;  // N = 64 = P
        out_imag[row * Pq + col] = x_imag[row * Pq + col] + acc[j][r];
      }
  }
}

// ---------------------------------------------------------------------------
extern "C" void kernel_launch(void* const* d_in, const int* in_sizes, int n_in,
                              void* d_out, int out_size, void* d_ws,
                              size_t ws_size, hipStream_t stream) {
  const float* x_real   = (const float*)d_in[0];  // (B,L,D)
  const float* x_imag   = (const float*)d_in[1];  // (B,L,P)
  const float* pos_freq = (const float*)d_in[2];  // (L,P)
  const float* W_up     = (const float*)d_in[3];  // (D,H)
  const float* wq       = (const float*)d_in[4];  // (P,H)
  const float* bq       = (const float*)d_in[5];  // (P,H)
  const float* Wdr      = (const float*)d_in[6];  // (H,D)
  const float* Wdi      = (const float*)d_in[7];  // (H,P)

  float* out_real = (float*)d_out;            // (B,L,D)
  float* out_imag = out_real + BLq * Dq;      // (B,L,P)

  char* ws = (char*)d_ws;
  short* gate_bf = (short*)ws;                      // 4 MB  [BL][H] bf16
  short* outbf   = (short*)(ws + (4u << 20));       // 4 MB  [BL][H] bf16
  short* wupT    = (short*)(ws + (8u << 20));       // 2 MB  [H][D]  bf16
  short* wdrT    = (short*)(ws + (10u << 20));      // 2 MB  [D][H]  bf16
  short* xrbf    = (short*)(ws + (12u << 20));      // 1 MB  [BL][D] bf16
  short* wdiT    = (short*)(ws + (13u << 20));      // 256KB [P][H]  bf16

  fused_prologue<<<3712, 256, 0, stream>>>(
      x_real, x_imag, pos_freq, W_up, wq, bq, Wdr, Wdi,
      wupT, wdrT, wdiT, xrbf, gate_bf);

  fused_up<<<1024, 256, 0, stream>>>(xrbf, wupT, gate_bf, outbf);

  fused_down<<<288, 256, 0, stream>>>(
      outbf, wdrT, gate_bf, wdiT, x_real, x_imag, out_real, out_imag);
}